// Round 1
// baseline (3004.050 us; speedup 1.0000x reference)
//
#include <hip/hip_runtime.h>
#include <hip/hip_bf16.h>
#include <stdint.h>

// 2-layer LSTM, B=1024 T=80 E=100 U=512, bf16 MFMA path.
// Per call: embed+pad -> bf16, transpose weights -> bf16 [n][k], then 80x2 fused
// GEMM+LSTM-cell kernels (h ping-pong bf16, c in-place fp32), final dense+sigmoid.

#define B_ 1024
#define T_ 80
#define E_ 100
#define EP_ 128
#define U_ 512

using bf16 = __hip_bfloat16;
typedef __attribute__((ext_vector_type(8))) short short8;
typedef __attribute__((ext_vector_type(4))) float f32x4;

__device__ __forceinline__ float sigf(float x) { return 1.f / (1.f + __expf(-x)); }
__device__ __forceinline__ float tanh_f(float x) { return 2.f / (1.f + __expf(-2.f * x)) - 1.f; }

// XP[t][b][e] (e padded to 128 with zeros), bf16
__global__ void embed_kernel(const int* __restrict__ tokens, const float* __restrict__ emb,
                             bf16* __restrict__ XP) {
  int idx = blockIdx.x * 256 + threadIdx.x;  // over T_*B_*128 = 10485760
  int e = idx & 127;
  int bt = idx >> 7;
  int b = bt & (B_ - 1);
  int t = bt >> 10;
  if (t >= T_) return;
  int tok = tokens[b * T_ + t];
  float v = (e < E_) ? emb[tok * E_ + e] : 0.f;
  XP[idx] = __float2bfloat16(v);
}

// W [Kreal][2048] fp32 -> WT [2048][Kp] bf16 (rows k>=Kreal zero-padded)
__global__ void transpose_kernel(const float* __restrict__ W, bf16* __restrict__ WT,
                                 int Kreal, int Kp) {
  int idx = blockIdx.x * 256 + threadIdx.x;  // over 2048*Kp
  int n = idx / Kp;
  int k = idx - n * Kp;
  float v = (k < Kreal) ? W[k * 2048 + n] : 0.f;
  WT[idx] = __float2bfloat16(v);
}

// One LSTM cell step: z = A0@B0^T-seg + A1@B1^T-seg (+bias), gates, update C (fp32,
// in-place) and Hout (bf16). A segments: [A0 cols 0..nkt0*32) ++ [A1 ...].
// B0/B1 are [2048][ld] bf16, n-major (transposed weights).
// Grid: (16, 32). Block tile: 64 rows x 16 units (64 z-cols: 4 gates x 16).
__global__ __launch_bounds__(256) void lstm_cell_kernel(
    const bf16* __restrict__ A0, int lda0, const bf16* __restrict__ B0, int ldb0, int nkt0,
    const bf16* __restrict__ A1, int lda1, const bf16* __restrict__ B1, int ldb1, int nkt1,
    const float* __restrict__ bias, float* __restrict__ Cst, bf16* __restrict__ Hout) {
  __shared__ alignas(16) char smem[64 * 68 * 4];  // 17408 B; staging uses first 8192
  const int tid = threadIdx.x;
  const int w = tid >> 6;   // wave 0..3
  const int l = tid & 63;
  const int q = l >> 4;     // k-chunk / quad
  const int m = l & 15;
  const int bm = blockIdx.x;       // 64-row tile
  const int u0 = blockIdx.y * 16;  // unit offset
  const int wm = w & 1;            // wave's 32-row group
  const int wn = w >> 1;           // wave's 32-col group

  f32x4 acc00 = {0.f, 0.f, 0.f, 0.f};
  f32x4 acc01 = {0.f, 0.f, 0.f, 0.f};
  f32x4 acc10 = {0.f, 0.f, 0.f, 0.f};
  f32x4 acc11 = {0.f, 0.f, 0.f, 0.f};

  char* sA = smem;
  char* sB = smem + 4096;
  const int sOff = w * 1024 + l * 16;  // == w*1024 + q*256 + m*16 (chunk-major)
  const int fA0 = (wm * 2 + 0) * 1024 + q * 256 + m * 16;
  const int fA1 = (wm * 2 + 1) * 1024 + q * 256 + m * 16;
  const int fB0 = (wn * 2 + 0) * 1024 + q * 256 + m * 16;
  const int fB1 = (wn * 2 + 1) * 1024 + q * 256 + m * 16;

  const int nkt = nkt0 + nkt1;
  for (int kt = 0; kt < nkt; ++kt) {
    const bf16* Ap; int lda; const bf16* Bp; int ldb; int k0;
    if (kt < nkt0) { Ap = A0; lda = lda0; Bp = B0; ldb = ldb0; k0 = kt * 32; }
    else           { Ap = A1; lda = lda1; Bp = B1; ldb = ldb1; k0 = (kt - nkt0) * 32; }
    // stage A rows bm*64+16w+m (k-chunk q), B n-rows gate=w, unit u0+m (k-chunk q)
    const uint4 av = *(const uint4*)(Ap + (size_t)(bm * 64 + w * 16 + m) * lda + k0 + q * 8);
    const uint4 bv = *(const uint4*)(Bp + (size_t)(w * 512 + u0 + m) * ldb + k0 + q * 8);
    __syncthreads();  // previous iter's frag reads done
    *(uint4*)(sA + sOff) = av;
    *(uint4*)(sB + sOff) = bv;
    __syncthreads();
    short8 a0 = *(const short8*)(sA + fA0);
    short8 a1 = *(const short8*)(sA + fA1);
    short8 b0 = *(const short8*)(sB + fB0);
    short8 b1 = *(const short8*)(sB + fB1);
    acc00 = __builtin_amdgcn_mfma_f32_16x16x32_bf16(a0, b0, acc00, 0, 0, 0);
    acc01 = __builtin_amdgcn_mfma_f32_16x16x32_bf16(a0, b1, acc01, 0, 0, 0);
    acc10 = __builtin_amdgcn_mfma_f32_16x16x32_bf16(a1, b0, acc10, 0, 0, 0);
    acc11 = __builtin_amdgcn_mfma_f32_16x16x32_bf16(a1, b1, acc11, 0, 0, 0);
  }

  __syncthreads();
  float* zs = (float*)smem;  // [64][68] (pad 4 to break bank strides)
#pragma unroll
  for (int r = 0; r < 4; ++r) {
    int rr = q * 4 + r;
    zs[(wm * 32 + rr) * 68 + wn * 32 + m] = acc00[r];
    zs[(wm * 32 + rr) * 68 + wn * 32 + 16 + m] = acc01[r];
    zs[(wm * 32 + 16 + rr) * 68 + wn * 32 + m] = acc10[r];
    zs[(wm * 32 + 16 + rr) * 68 + wn * 32 + 16 + m] = acc11[r];
  }
  __syncthreads();

  // epilogue: cols n = gate*16 + uu; thread handles (uu = tid&15, rows tid>>4 + 16p)
  const int uu = tid & 15;
  const int r0 = tid >> 4;
  const int gu = u0 + uu;
  const float bi = bias[0 * 512 + gu];
  const float bf = bias[1 * 512 + gu];
  const float bg = bias[2 * 512 + gu];
  const float bo = bias[3 * 512 + gu];
#pragma unroll
  for (int p = 0; p < 4; ++p) {
    int row = r0 + p * 16;
    float zi = zs[row * 68 + 0 + uu] + bi;
    float zf = zs[row * 68 + 16 + uu] + bf;
    float zg = zs[row * 68 + 32 + uu] + bg;
    float zo = zs[row * 68 + 48 + uu] + bo;
    size_t gi = (size_t)(bm * 64 + row) * 512 + gu;
    float c = sigf(zf) * Cst[gi] + sigf(zi) * tanh_f(zg);
    float h = sigf(zo) * tanh_f(c);
    Cst[gi] = c;
    Hout[gi] = __float2bfloat16(h);
  }
}

// out[b] = sigmoid(h2[b,:] @ Wout + bout); one wave per row
__global__ void output_kernel(const bf16* __restrict__ H2, const float* __restrict__ Wout,
                              const float* __restrict__ bout, float* __restrict__ out) {
  int w = threadIdx.x >> 6, l = threadIdx.x & 63;
  int row = blockIdx.x * 4 + w;
  const bf16* h = H2 + (size_t)row * 512;
  float s = 0.f;
#pragma unroll
  for (int k = 0; k < 8; ++k) {
    int kk = l + k * 64;
    s += __bfloat162float(h[kk]) * Wout[kk];
  }
#pragma unroll
  for (int off = 32; off > 0; off >>= 1) s += __shfl_down(s, off);
  if (l == 0) out[row] = sigf(s + bout[0]);
}

extern "C" void kernel_launch(void* const* d_in, const int* in_sizes, int n_in,
                              void* d_out, int out_size, void* d_ws, size_t ws_size,
                              hipStream_t stream) {
  const int* tokens = (const int*)d_in[0];
  const float* emb = (const float*)d_in[1];
  const float* W1 = (const float*)d_in[2];
  const float* U1 = (const float*)d_in[3];
  const float* b1 = (const float*)d_in[4];
  const float* W2 = (const float*)d_in[5];
  const float* U2 = (const float*)d_in[6];
  const float* b2 = (const float*)d_in[7];
  const float* Wout = (const float*)d_in[8];
  const float* bout = (const float*)d_in[9];
  float* out = (float*)d_out;
  char* ws = (char*)d_ws;

  // workspace layout (bytes)
  const size_t oXP = 0;                       // 80*1024*128 bf16 = 20971520
  const size_t oW1T = 20971520;               // 2048*128 bf16   = 524288
  const size_t oU1T = 21495808;               // 2048*512 bf16   = 2097152
  const size_t oW2T = 23592960;               // 2097152
  const size_t oU2T = 25690112;               // 2097152
  const size_t oH1 = 27787264;                // 2 x 1024*512 bf16 = 2097152
  const size_t oH2 = 29884416;                // 2097152
  const size_t oC1 = 31981568;                // 1024*512 f32 = 2097152
  const size_t oC2 = 34078720;                // 2097152  (end 36175872)
  if (ws_size < 36175872) return;

  bf16* XP = (bf16*)(ws + oXP);
  bf16* W1T = (bf16*)(ws + oW1T);
  bf16* U1T = (bf16*)(ws + oU1T);
  bf16* W2T = (bf16*)(ws + oW2T);
  bf16* U2T = (bf16*)(ws + oU2T);
  bf16* H1 = (bf16*)(ws + oH1);  // buffers: +0 / +524288 elems
  bf16* H2 = (bf16*)(ws + oH2);
  float* C1 = (float*)(ws + oC1);
  float* C2 = (float*)(ws + oC2);

  // zero initial states (ws is poisoned before every launch)
  hipMemsetAsync(ws + oH1, 0, 1048576, stream);      // H1 buf0
  hipMemsetAsync(ws + oH2, 0, 1048576, stream);      // H2 buf0
  hipMemsetAsync(ws + oC1, 0, 4194304, stream);      // C1 + C2

  embed_kernel<<<40960, 256, 0, stream>>>(tokens, emb, XP);
  transpose_kernel<<<1024, 256, 0, stream>>>(W1, W1T, 100, 128);
  transpose_kernel<<<4096, 256, 0, stream>>>(U1, U1T, 512, 512);
  transpose_kernel<<<4096, 256, 0, stream>>>(W2, W2T, 512, 512);
  transpose_kernel<<<4096, 256, 0, stream>>>(U2, U2T, 512, 512);

  dim3 grid(16, 32);
  for (int t = 0; t < T_; ++t) {
    int cur = t & 1, nxt = cur ^ 1;
    // layer 1: z1 = x_t @ W1 + h1 @ U1 + b1
    lstm_cell_kernel<<<grid, 256, 0, stream>>>(
        XP + (size_t)t * 131072, 128, W1T, 128, 4,
        H1 + (size_t)cur * 524288, 512, U1T, 512, 16,
        b1, C1, H1 + (size_t)nxt * 524288);
    // layer 2: z2 = h1_new @ W2 + h2 @ U2 + b2
    lstm_cell_kernel<<<grid, 256, 0, stream>>>(
        H1 + (size_t)nxt * 524288, 512, W2T, 512, 16,
        H2 + (size_t)cur * 524288, 512, U2T, 512, 16,
        b2, C2, H2 + (size_t)nxt * 524288);
  }
  // final h2 lives in buffer (T_) & 1 == 0
  output_kernel<<<256, 256, 0, stream>>>(H2, Wout, bout, out);
}

// Round 2
// 2366.286 us; speedup vs baseline: 1.2695x; 1.2695x over previous
//
#include <hip/hip_runtime.h>
#include <hip/hip_bf16.h>
#include <stdint.h>

// 2-layer LSTM, B=1024 T=80 E=100 U=512, bf16 MFMA path.
// R1: software-pipeline across timesteps — one launch runs layer2(t-1) || layer1(t)
// (independent): 81 dependent launches instead of 161, 4 blocks/CU. K-loop is
// double-buffered with global_load_lds (16B) async staging, one barrier/iter.

#define B_ 1024
#define T_ 80

using bf16 = __hip_bfloat16;
typedef __attribute__((ext_vector_type(8))) short short8;
typedef __attribute__((ext_vector_type(4))) float f32x4;

__device__ __forceinline__ float sigf(float x) { return 1.f / (1.f + __expf(-x)); }
__device__ __forceinline__ float tanh_f(float x) { return 2.f / (1.f + __expf(-2.f * x)) - 1.f; }

typedef const __attribute__((address_space(1))) void* gp1_t;
typedef __attribute__((address_space(3))) void* lp3_t;
__device__ __forceinline__ void llds16(const void* g, void* l) {
  // per-lane global gather -> LDS wave-uniform base + lane*16
  __builtin_amdgcn_global_load_lds((gp1_t)g, (lp3_t)l, 16, 0, 0);
}

// XP[t][b][e] (e padded to 128 with zeros), bf16
__global__ void embed_kernel(const int* __restrict__ tokens, const float* __restrict__ emb,
                             bf16* __restrict__ XP) {
  int idx = blockIdx.x * 256 + threadIdx.x;  // over T_*B_*128
  int e = idx & 127;
  int bt = idx >> 7;
  int b = bt & (B_ - 1);
  int t = bt >> 10;
  if (t >= T_) return;
  int tok = tokens[b * T_ + t];
  float v = (e < 100) ? emb[tok * 100 + e] : 0.f;
  XP[idx] = __float2bfloat16(v);
}

// W [Kreal][2048] fp32 -> WT [2048][Kp] bf16, coalesced both ways via 32x32 LDS tile
__global__ void transpose_kernel(const float* __restrict__ W, bf16* __restrict__ WT,
                                 int Kreal, int Kp) {
  __shared__ float tile[32][33];
  int tn = blockIdx.x * 32;
  int tk = blockIdx.y * 32;
  int lx = threadIdx.x & 31;
  int ly = threadIdx.x >> 5;  // 8
#pragma unroll
  for (int r = ly; r < 32; r += 8) {
    int k = tk + r;
    tile[r][lx] = (k < Kreal) ? W[(size_t)k * 2048 + tn + lx] : 0.f;
  }
  __syncthreads();
#pragma unroll
  for (int r = ly; r < 32; r += 8) {
    WT[(size_t)(tn + r) * Kp + tk + lx] = __float2bfloat16(tile[lx][r]);
  }
}

struct CellParams {
  const bf16* A0; const bf16* B0;
  const bf16* A1; const bf16* B1;
  int lda0, ldb0, nkt0, lda1, ldb1, nkt1;
  const float* bias; float* C; bf16* H;
};

// z = A0@B0^T-seg + A1@B1^T-seg + bias; gates i,f,g,o; C fp32 in-place; H bf16 out.
// Block tile 64 rows x 16 units (64 z-cols). Dual-cell: blocks 0..511 -> p0,
// 512..1023 -> p1. LDS: 2 x (4KB A + 4KB B) staging, reused as 64x68 f32 z.
__global__ __launch_bounds__(256) void cell_kernel(CellParams p0, CellParams p1) {
  __shared__ alignas(16) char smem[17408];
  const CellParams& p = (blockIdx.x >> 9) ? p1 : p0;
  const int bid = blockIdx.x & 511;
  const int bm = bid & 15;         // 64-row tile
  const int u0 = (bid >> 4) * 16;  // unit offset
  const int tid = threadIdx.x;
  const int w = tid >> 6, l = tid & 63, q = l >> 4, m = l & 15;
  const int wm = w & 1, wn = w >> 1;

  // staging row pointers: wave w stages A rows w*16+m and B n-rows gate w, unit u0+m
  const bf16* arow0 = p.A0 + (size_t)(bm * 64 + w * 16 + m) * p.lda0;
  const bf16* brow0 = p.B0 + (size_t)(w * 512 + u0 + m) * p.ldb0;
  const bf16* arow1 = p.A1 + (size_t)(bm * 64 + w * 16 + m) * p.lda1;
  const bf16* brow1 = p.B1 + (size_t)(w * 512 + u0 + m) * p.ldb1;
  const int woff = w * 1024;  // lane l lands at woff + l*16 (== q*256 + m*16)

  auto stage = [&](int kt, int buf) {
    const bf16 *ga, *gb;
    if (kt < p.nkt0) { int k0 = kt * 32 + q * 8; ga = arow0 + k0; gb = brow0 + k0; }
    else { int k0 = (kt - p.nkt0) * 32 + q * 8; ga = arow1 + k0; gb = brow1 + k0; }
    char* base = smem + buf * 8192 + woff;
    llds16(ga, base);          // A: [16-row group w][chunk q][m][16B]
    llds16(gb, base + 4096);   // B: same layout, n-rows
  };

  f32x4 acc00 = {0.f, 0.f, 0.f, 0.f};
  f32x4 acc01 = {0.f, 0.f, 0.f, 0.f};
  f32x4 acc10 = {0.f, 0.f, 0.f, 0.f};
  f32x4 acc11 = {0.f, 0.f, 0.f, 0.f};

  const int fA0 = wm * 2048 + q * 256 + m * 16;
  const int fA1 = fA0 + 1024;
  const int fB0 = 4096 + wn * 2048 + q * 256 + m * 16;
  const int fB1 = fB0 + 1024;

  const int total = p.nkt0 + p.nkt1;
  stage(0, 0);
  for (int kt = 0; kt < total; ++kt) {
    const int cb = (kt & 1) * 8192;
    __syncthreads();                         // drains this wave's loads (vmcnt0) + barrier
    if (kt + 1 < total) stage(kt + 1, (kt + 1) & 1);  // async prefetch, lands by next barrier
    short8 a0 = *(const short8*)(smem + cb + fA0);
    short8 a1 = *(const short8*)(smem + cb + fA1);
    short8 b0 = *(const short8*)(smem + cb + fB0);
    short8 b1 = *(const short8*)(smem + cb + fB1);
    acc00 = __builtin_amdgcn_mfma_f32_16x16x32_bf16(a0, b0, acc00, 0, 0, 0);
    acc01 = __builtin_amdgcn_mfma_f32_16x16x32_bf16(a0, b1, acc01, 0, 0, 0);
    acc10 = __builtin_amdgcn_mfma_f32_16x16x32_bf16(a1, b0, acc10, 0, 0, 0);
    acc11 = __builtin_amdgcn_mfma_f32_16x16x32_bf16(a1, b1, acc11, 0, 0, 0);
  }

  __syncthreads();
  float* zs = (float*)smem;  // [64][68]
#pragma unroll
  for (int r = 0; r < 4; ++r) {
    int rr = q * 4 + r;
    zs[(wm * 32 + rr) * 68 + wn * 32 + m] = acc00[r];
    zs[(wm * 32 + rr) * 68 + wn * 32 + 16 + m] = acc01[r];
    zs[(wm * 32 + 16 + rr) * 68 + wn * 32 + m] = acc10[r];
    zs[(wm * 32 + 16 + rr) * 68 + wn * 32 + 16 + m] = acc11[r];
  }
  __syncthreads();

  const int uu = tid & 15;
  const int r0 = tid >> 4;
  const int gu = u0 + uu;
  const float bi = p.bias[0 * 512 + gu];
  const float bf = p.bias[1 * 512 + gu];
  const float bg = p.bias[2 * 512 + gu];
  const float bo = p.bias[3 * 512 + gu];
#pragma unroll
  for (int pp = 0; pp < 4; ++pp) {
    int row = r0 + pp * 16;
    float zi = zs[row * 68 + 0 + uu] + bi;
    float zf = zs[row * 68 + 16 + uu] + bf;
    float zg = zs[row * 68 + 32 + uu] + bg;
    float zo = zs[row * 68 + 48 + uu] + bo;
    size_t gi = (size_t)(bm * 64 + row) * 512 + gu;
    float c = sigf(zf) * p.C[gi] + sigf(zi) * tanh_f(zg);
    float h = sigf(zo) * tanh_f(c);
    p.C[gi] = c;
    p.H[gi] = __float2bfloat16(h);
  }
}

// out[b] = sigmoid(h2[b,:] @ Wout + bout); one wave per row
__global__ void output_kernel(const bf16* __restrict__ H2, const float* __restrict__ Wout,
                              const float* __restrict__ bout, float* __restrict__ out) {
  int w = threadIdx.x >> 6, l = threadIdx.x & 63;
  int row = blockIdx.x * 4 + w;
  const bf16* h = H2 + (size_t)row * 512;
  float s = 0.f;
#pragma unroll
  for (int k = 0; k < 8; ++k) {
    int kk = l + k * 64;
    s += __bfloat162float(h[kk]) * Wout[kk];
  }
#pragma unroll
  for (int off = 32; off > 0; off >>= 1) s += __shfl_down(s, off);
  if (l == 0) out[row] = sigf(s + bout[0]);
}

extern "C" void kernel_launch(void* const* d_in, const int* in_sizes, int n_in,
                              void* d_out, int out_size, void* d_ws, size_t ws_size,
                              hipStream_t stream) {
  const int* tokens = (const int*)d_in[0];
  const float* emb = (const float*)d_in[1];
  const float* W1 = (const float*)d_in[2];
  const float* U1 = (const float*)d_in[3];
  const float* b1 = (const float*)d_in[4];
  const float* W2 = (const float*)d_in[5];
  const float* U2 = (const float*)d_in[6];
  const float* b2 = (const float*)d_in[7];
  const float* Wout = (const float*)d_in[8];
  const float* bout = (const float*)d_in[9];
  float* out = (float*)d_out;
  char* ws = (char*)d_ws;

  const size_t oXP = 0;          // 80*1024*128 bf16 = 20971520
  const size_t oW1T = 20971520;  // 2048*128 bf16
  const size_t oU1T = 21495808;  // 2048*512 bf16
  const size_t oW2T = 23592960;
  const size_t oU2T = 25690112;
  const size_t oH1 = 27787264;   // 2 x 1024*512 bf16
  const size_t oH2 = 29884416;
  const size_t oC1 = 31981568;   // 1024*512 f32
  const size_t oC2 = 34078720;
  if (ws_size < 36175872) return;

  bf16* XP = (bf16*)(ws + oXP);
  bf16* W1T = (bf16*)(ws + oW1T);
  bf16* U1T = (bf16*)(ws + oU1T);
  bf16* W2T = (bf16*)(ws + oW2T);
  bf16* U2T = (bf16*)(ws + oU2T);
  bf16* H1 = (bf16*)(ws + oH1);
  bf16* H2 = (bf16*)(ws + oH2);
  float* C1 = (float*)(ws + oC1);
  float* C2 = (float*)(ws + oC2);

  hipMemsetAsync(ws + oH1, 0, 1048576, stream);  // H1 buf0
  hipMemsetAsync(ws + oH2, 0, 1048576, stream);  // H2 buf0
  hipMemsetAsync(ws + oC1, 0, 4194304, stream);  // C1 + C2

  embed_kernel<<<40960, 256, 0, stream>>>(tokens, emb, XP);
  transpose_kernel<<<dim3(64, 4), 256, 0, stream>>>(W1, W1T, 100, 128);
  transpose_kernel<<<dim3(64, 16), 256, 0, stream>>>(U1, U1T, 512, 512);
  transpose_kernel<<<dim3(64, 16), 256, 0, stream>>>(W2, W2T, 512, 512);
  transpose_kernel<<<dim3(64, 16), 256, 0, stream>>>(U2, U2T, 512, 512);

  auto mkL1 = [&](int t) {
    CellParams p;
    p.A0 = XP + (size_t)t * 131072; p.B0 = W1T; p.lda0 = 128; p.ldb0 = 128; p.nkt0 = 4;
    p.A1 = H1 + (size_t)(t & 1) * 524288; p.B1 = U1T; p.lda1 = 512; p.ldb1 = 512; p.nkt1 = 16;
    p.bias = b1; p.C = C1; p.H = H1 + (size_t)((t + 1) & 1) * 524288;
    return p;
  };
  auto mkL2 = [&](int t) {
    CellParams p;
    p.A0 = H1 + (size_t)((t + 1) & 1) * 524288; p.B0 = W2T; p.lda0 = 512; p.ldb0 = 512; p.nkt0 = 16;
    p.A1 = H2 + (size_t)(t & 1) * 524288; p.B1 = U2T; p.lda1 = 512; p.ldb1 = 512; p.nkt1 = 16;
    p.bias = b2; p.C = C2; p.H = H2 + (size_t)((t + 1) & 1) * 524288;
    return p;
  };

  cell_kernel<<<512, 256, 0, stream>>>(mkL1(0), mkL1(0));
  for (int k = 1; k < T_; ++k)
    cell_kernel<<<1024, 256, 0, stream>>>(mkL2(k - 1), mkL1(k));  // layer2(k-1) || layer1(k)
  cell_kernel<<<512, 256, 0, stream>>>(mkL2(T_ - 1), mkL2(T_ - 1));

  // final h2 in buffer (T_&1)==0
  output_kernel<<<256, 256, 0, stream>>>(H2, Wout, bout, out);
}